// Round 10
// baseline (2484.897 us; speedup 1.0000x reference)
//
#include <hip/hip_runtime.h>
#include <stdint.h>

typedef unsigned short u16;
typedef short bf16x8 __attribute__((ext_vector_type(8)));
typedef float f32x4 __attribute__((ext_vector_type(4)));

#define DEV __device__ __forceinline__

DEV float bf2f(u16 u){ union{uint32_t i; float f;} v; v.i = ((uint32_t)u)<<16; return v.f; }
DEV u16 f2bf(float f){ union{float f; uint32_t i;} v; v.f=f; uint32_t u=v.i; u += 0x7FFFu + ((u>>16)&1u); return (u16)(u>>16); }
// HW packed f32->bf16 (RNE), 1 VALU op per 2 conversions
DEV uint32_t cvt_pk_bf16(float lo, float hi){
    uint32_t r;
    asm("v_cvt_pk_bf16_f32 %0, %1, %2" : "=v"(r) : "v"(lo), "v"(hi));
    return r;
}
DEV bf16x8 pack8(const float* v){
    union { bf16x8 b; uint32_t u[4]; } o;
    #pragma unroll
    for (int k=0;k<4;k++) o.u[k] = cvt_pk_bf16(v[2*k], v[2*k+1]);
    return o.b;
}
DEV float fast_tanh(float x){ float t=__builtin_amdgcn_exp2f(x*2.885390081777927f); return 1.f-2.f*__builtin_amdgcn_rcpf(t+1.f); }
DEV float fast_sigmoid(float x){ return __builtin_amdgcn_rcpf(1.f+__builtin_amdgcn_exp2f(-1.4426950408889634f*x)); }
DEV f32x4 mfma16(bf16x8 a, bf16x8 b, f32x4 c){ return __builtin_amdgcn_mfma_f32_16x16x32_bf16(a,b,c,0,0,0); }
DEV void atomAddF(float* p, float v){ __hip_atomic_fetch_add(p, v, __ATOMIC_RELAXED, __HIP_MEMORY_SCOPE_AGENT); }
// LDS-only barrier: does NOT drain vmcnt -> prefetched global loads stay in flight
DEV void barrier_lds(){
    asm volatile("s_waitcnt lgkmcnt(0)" ::: "memory");
    __builtin_amdgcn_s_barrier();
    __builtin_amdgcn_sched_barrier(0);
}

__global__ void diag_kernel(float* out, float v){ if (threadIdx.x < 8) out[threadIdx.x] = v; }

// Transpose + bf16 + XOR-swizzle weight [K][Nn] (row stride ld) -> BT[n][k]
__global__ __launch_bounds__(256) void prep_wT(const float* __restrict__ src, int ld,
                                               u16* __restrict__ dst, int K, int Nn)
{
    int idx = blockIdx.x*256 + threadIdx.x;
    if (idx >= K*Nn) return;
    int n = idx / K, k = idx - n*K;
    dst[(n*K + k) ^ ((n&7)<<3)] = f2bf(src[(size_t)k*ld + n]);
}

// ---------------- CSR-by-dst build ----------------
__global__ __launch_bounds__(256) void hist_kernel(const int* __restrict__ dst,
                                                   int* __restrict__ deg, int E)
{
    int e = blockIdx.x*256 + threadIdx.x;
    if (e < E) atomicAdd(&deg[dst[e]], 1);
}

__global__ __launch_bounds__(1024) void scan_kernel(const int* __restrict__ deg,
                                                    int* __restrict__ cur, int N)
{
    __shared__ int sc[1024];
    int t = threadIdx.x;
    int chunk = (N + 1023) / 1024;
    int i0 = t * chunk, i1 = i0 + chunk; if (i1 > N) i1 = N;
    int s = 0;
    for (int i = i0; i < i1; i++) s += deg[i];
    sc[t] = s; __syncthreads();
    int own = s;
    for (int off = 1; off < 1024; off <<= 1){
        int v = (t >= off) ? sc[t - off] : 0;
        __syncthreads();
        sc[t] += v;
        __syncthreads();
    }
    int run = sc[t] - own;
    for (int i = i0; i < i1; i++){ cur[i] = run; run += deg[i]; }
}

__global__ __launch_bounds__(256) void scatter_kernel(
    const int* __restrict__ src, const int* __restrict__ dst, const float* __restrict__ ea,
    int* __restrict__ cur, int* __restrict__ src_s, int* __restrict__ dst_s,
    float* __restrict__ ea_s, int E)
{
    int e = blockIdx.x*256 + threadIdx.x;
    if (e >= E) return;
    int d = dst[e];
    int pos = atomicAdd(&cur[d], 1);
    src_s[pos] = src[e];
    dst_s[pos] = d;
    ea_s[(size_t)pos*3+0] = ea[(size_t)e*3+0];
    ea_s[(size_t)pos*3+1] = ea[(size_t)e*3+1];
    ea_s[(size_t)pos*3+2] = ea[(size_t)e*3+2];
}

// ---------------- node encoder ----------------
__global__ __launch_bounds__(256) void enc_kernel(
    const float* __restrict__ in3, int rows,
    const float* __restrict__ w1, const float* __restrict__ b1,
    const u16* __restrict__ w2T, const float* __restrict__ b2,
    const float* __restrict__ gam, const float* __restrict__ bet,
    float* __restrict__ outF)
{
    __shared__ u16 wbs[128*128];
    __shared__ u16 hid[64*128];
    int tid = threadIdx.x, r0 = blockIdx.x*64;
    for (int i = tid; i < 8192; i += 256) ((uint32_t*)wbs)[i] = ((const uint32_t*)w2T)[i];
    for (int idx = tid; idx < 8192; idx += 256) {
        int r = idx >> 7, c = idx & 127;
        int row = r0 + r; if (row > rows-1) row = rows-1;
        float v = b1[c] + in3[(size_t)row*3+0]*w1[c] + in3[(size_t)row*3+1]*w1[128+c] + in3[(size_t)row*3+2]*w1[256+c];
        hid[idx ^ ((r&7)<<3)] = f2bf(fmaxf(v, 0.f));
    }
    barrier_lds();
    int lane = tid & 63, w = tid >> 6, l16 = lane & 15, q = lane >> 4;
    int ar = 16*w + l16;
    f32x4 acc[8];
    #pragma unroll
    for (int nt=0; nt<8; nt++) acc[nt] = (f32x4){0.f,0.f,0.f,0.f};
    #pragma unroll
    for (int ks=0; ks<4; ks++) {
        bf16x8 af = *(const bf16x8*)&hid[(ar*128 + ks*32 + q*8) ^ ((ar&7)<<3)];
        #pragma unroll
        for (int nt=0; nt<8; nt++) {
            int n = nt*16 + l16;
            bf16x8 bfr = *(const bf16x8*)&wbs[(n*128 + ks*32 + q*8) ^ ((n&7)<<3)];
            acc[nt] = mfma16(af, bfr, acc[nt]);
        }
    }
    float b2v[8], gv[8], bv[8];
    #pragma unroll
    for (int nt=0; nt<8; nt++){ int c = nt*16+l16; b2v[nt]=b2[c]; gv[nt]=gam[c]; bv[nt]=bet[c]; }
    #pragma unroll
    for (int reg=0; reg<4; reg++) {
        float s=0.f, ss=0.f;
        #pragma unroll
        for (int nt=0; nt<8; nt++){ float v = acc[nt][reg] + b2v[nt]; acc[nt][reg]=v; s+=v; ss+=v*v; }
        #pragma unroll
        for (int m=1; m<16; m<<=1){ s += __shfl_xor(s,m); ss += __shfl_xor(ss,m); }
        float mean = s * (1.f/128.f);
        float rstd = __builtin_amdgcn_rsqf(ss*(1.f/128.f) - mean*mean + 1e-5f);
        int row = r0 + 16*w + 4*q + reg;
        if (row < rows) {
            #pragma unroll
            for (int nt=0; nt<8; nt++){
                int c = nt*16+l16;
                outF[(size_t)row*128 + c] = (acc[nt][reg]-mean)*rstd*gv[nt] + bv[nt];
            }
        }
    }
}

// ---------------- dst-sorted message pass v2 ----------------
__global__ __launch_bounds__(256) void msg_v2(
    const float* __restrict__ ea_s, const int* __restrict__ src_s, const int* __restrict__ dst_s,
    const float* __restrict__ ew1, const float* __restrict__ eb1,
    const u16* __restrict__ ew2T, const float* __restrict__ eb2,
    const float* __restrict__ eg, const float* __restrict__ ebe,
    const float* __restrict__ h, float* __restrict__ agg, int E)
{
    __shared__ float lag[8192];      // 32KB: ew2T (u16) during GEMM, then f32 agg slots
    __shared__ u16 hid[64*128];      // 16KB e-tile
    __shared__ float eas[192];
    __shared__ float w1s[384];
    __shared__ float b1s[128];
    __shared__ int ssrc[64], sdv[64], sslot[64], sfl[64];
    u16* wbs = (u16*)lag;
    int tid = threadIdx.x, r0 = blockIdx.x*64;

    const uint4* w4 = (const uint4*)ew2T;
    uint4 pr[8];
    #pragma unroll
    for (int k=0;k<8;k++) pr[k] = w4[tid + k*256];

    if (tid < 192){ int gi = r0*3 + tid; eas[tid] = (gi < E*3) ? ea_s[gi] : 0.f; }
    if (tid < 128) b1s[tid] = eb1[tid];
    for (int i = tid; i < 384; i += 256) w1s[i] = ew1[i];
    if (tid < 64){
        int r = tid, ge = r0 + r;
        int valid = ge < E;
        int gc = valid ? ge : E-1;
        int dv = dst_s[gc];
        int sv = src_s[gc];
        int pin = __shfl_up(dv, 1);
        int head = (r == 0) || (dv != pin);
        int prevLast  = (r0 > 0)      ? dst_s[r0-1]  : -2;
        int nextFirst = (r0 + 64 < E) ? dst_s[r0+64] : -2;
        int interior = (dv != prevLast) && (dv != nextFirst);
        int s = head ? r : 0;
        #pragma unroll
        for (int off=1; off<64; off<<=1){ int v = __shfl_up(s, off); if (r >= off) s = (s > v ? s : v); }
        ssrc[r]=sv; sdv[r]=dv; sslot[r]=s;
        sfl[r] = ((head && valid)?1:0) | (interior?2:0) | (valid?4:0);
    }
    barrier_lds();
    {
        uint4* wb4 = (uint4*)wbs;
        #pragma unroll
        for (int k=0;k<8;k++) wb4[tid + k*256] = pr[k];
    }
    barrier_lds();

    int lane = tid&63, w = tid>>6, l16 = lane&15, q = lane>>4;
    int ar = 16*w + l16;
    float ea0 = eas[ar*3], ea1 = eas[ar*3+1], ea2 = eas[ar*3+2];
    f32x4 acc[8];
    #pragma unroll
    for (int nt=0; nt<8; nt++) acc[nt] = (f32x4){0.f,0.f,0.f,0.f};
    #pragma unroll
    for (int ks=0; ks<4; ks++){
        float hv8[8];
        #pragma unroll
        for (int j=0;j<8;j++){
            int c = ks*32 + q*8 + j;
            hv8[j] = fmaxf(b1s[c] + ea0*w1s[c] + ea1*w1s[128+c] + ea2*w1s[256+c], 0.f);
        }
        bf16x8 ah = pack8(hv8);
        #pragma unroll
        for (int nt=0; nt<8; nt++){
            int n = nt*16 + l16;
            bf16x8 bfr = *(const bf16x8*)&wbs[(n*128 + ks*32 + q*8) ^ ((n&7)<<3)];
            acc[nt] = mfma16(ah, bfr, acc[nt]);
        }
    }
    {   // LN -> e-tile into hid (plain layout; C/D rows wave-local)
        float b2v[8], gv[8], bv[8];
        #pragma unroll
        for (int nt=0; nt<8; nt++){ int c = nt*16+l16; b2v[nt]=eb2[c]; gv[nt]=eg[c]; bv[nt]=ebe[c]; }
        #pragma unroll
        for (int reg=0; reg<4; reg++){
            float s=0.f, ss=0.f;
            #pragma unroll
            for (int nt=0; nt<8; nt++){ float v = acc[nt][reg] + b2v[nt]; acc[nt][reg]=v; s+=v; ss+=v*v; }
            #pragma unroll
            for (int m=1; m<16; m<<=1){ s += __shfl_xor(s,m); ss += __shfl_xor(ss,m); }
            float mean = s*(1.f/128.f);
            float rstd = __builtin_amdgcn_rsqf(ss*(1.f/128.f)-mean*mean+1e-5f);
            int rl = 16*w + 4*q + reg;
            #pragma unroll
            for (int nt=0; nt<8; nt+=2){
                float v0 = (acc[nt][reg]-mean)*rstd*gv[nt] + bv[nt];
                float v1 = (acc[nt+1][reg]-mean)*rstd*gv[nt+1] + bv[nt+1];
                uint32_t pk = cvt_pk_bf16(v0, v1);
                hid[rl*128 + nt*16 + l16]     = (u16)pk;
                hid[rl*128 + (nt+1)*16 + l16] = (u16)(pk >> 16);
            }
        }
    }
    barrier_lds();
    for (int i = tid; i < 8192; i += 256) lag[i] = 0.f;
    barrier_lds();

    {   // message phase: 8 contiguous edges per thread, register run-accumulation
        int g = tid >> 5, cg = (tid & 31) << 2;
        float4 hv[8];
        #pragma unroll
        for (int k=0;k<8;k++)
            hv[k] = *(const float4*)(h + (size_t)ssrc[g*8+k]*128 + cg);
        float4 a = {0.f,0.f,0.f,0.f};
        int cur = -1;
        #pragma unroll
        for (int k=0;k<8;k++){
            int r = g*8 + k;
            if (sfl[r] & 4){
                uint2 ev = *(const uint2*)&hid[r*128 + cg];
                float4 m;
                m.x = fmaxf(hv[k].x + bf2f((u16)(ev.x & 0xFFFF)), 0.f);
                m.y = fmaxf(hv[k].y + bf2f((u16)(ev.x >> 16)),   0.f);
                m.z = fmaxf(hv[k].z + bf2f((u16)(ev.y & 0xFFFF)), 0.f);
                m.w = fmaxf(hv[k].w + bf2f((u16)(ev.y >> 16)),   0.f);
                int slot = sslot[r];
                if (slot != cur){
                    if (cur >= 0){
                        float* lp = lag + cur*128 + cg;
                        atomicAdd(lp+0,a.x); atomicAdd(lp+1,a.y); atomicAdd(lp+2,a.z); atomicAdd(lp+3,a.w);
                    }
                    cur = slot; a = m;
                } else {
                    a.x += m.x; a.y += m.y; a.z += m.z; a.w += m.w;
                }
            }
        }
        if (cur >= 0){
            float* lp = lag + cur*128 + cg;
            atomicAdd(lp+0,a.x); atomicAdd(lp+1,a.y); atomicAdd(lp+2,a.z); atomicAdd(lp+3,a.w);
        }
    }
    barrier_lds();
    for (int t = tid; t < 2048; t += 256){
        int r = t >> 5, cg = (t & 31) << 2;
        int fl = sfl[r];
        if (!(fl & 1)) continue;
        float4 v = *(const float4*)&lag[r*128 + cg];
        float* gp = agg + (size_t)sdv[r]*128 + cg;
        if (fl & 2){ *(float4*)gp = v; }
        else { atomAddF(gp+0,v.x); atomAddF(gp+1,v.y); atomAddF(gp+2,v.z); atomAddF(gp+3,v.w); }
    }
}

// ---------------- GINE update ----------------
__global__ __launch_bounds__(256) void gine_update(
    float* h, const float* __restrict__ agg,
    const float* __restrict__ epsArr, int layer,
    const u16* __restrict__ w1T, const u16* __restrict__ w2T,
    const float* __restrict__ b1, const float* __restrict__ b2,
    const float* __restrict__ gam, const float* __restrict__ bet,
    int rows, int doRelu)
{
    __shared__ u16 wbs[128*128];
    __shared__ u16 hid[64*128];
    int tid = threadIdx.x, r0 = blockIdx.x*64;
    float epsv = 1.f + epsArr[layer];
    for (int i = tid; i < 8192; i += 256) ((uint32_t*)wbs)[i] = ((const uint32_t*)w1T)[i];
    barrier_lds();
    int lane = tid&63, w = tid>>6, l16 = lane&15, q = lane>>4;
    int ar = 16*w + l16;
    int arow = r0 + ar;
    int arc = arow < rows ? arow : rows-1;
    f32x4 acc[8];
    #pragma unroll
    for (int nt=0; nt<8; nt++) acc[nt] = (f32x4){0.f,0.f,0.f,0.f};
    #pragma unroll
    for (int ks=0; ks<4; ks++){
        const float4* hp = (const float4*)(h   + (size_t)arc*128 + ks*32 + q*8);
        const float4* ap = (const float4*)(agg + (size_t)arc*128 + ks*32 + q*8);
        float4 h0 = hp[0], h1 = hp[1], a0 = ap[0], a1 = ap[1];
        float zv[8];
        zv[0]=fmaf(epsv,h0.x,a0.x); zv[1]=fmaf(epsv,h0.y,a0.y);
        zv[2]=fmaf(epsv,h0.z,a0.z); zv[3]=fmaf(epsv,h0.w,a0.w);
        zv[4]=fmaf(epsv,h1.x,a1.x); zv[5]=fmaf(epsv,h1.y,a1.y);
        zv[6]=fmaf(epsv,h1.z,a1.z); zv[7]=fmaf(epsv,h1.w,a1.w);
        bf16x8 af = pack8(zv);
        #pragma unroll
        for (int nt=0; nt<8; nt++){
            int n = nt*16 + l16;
            bf16x8 bfr = *(const bf16x8*)&wbs[(n*128 + ks*32 + q*8) ^ ((n&7)<<3)];
            acc[nt] = mfma16(af, bfr, acc[nt]);
        }
    }
    #pragma unroll
    for (int nt=0; nt<8; nt++){
        int c = nt*16 + l16; float b1v = b1[c];
        #pragma unroll
        for (int reg=0; reg<4; reg++){
            int rl = 16*w + 4*q + reg;
            hid[(rl*128 + c) ^ ((rl&7)<<3)] = f2bf(fmaxf(acc[nt][reg] + b1v, 0.f));
        }
    }
    barrier_lds();
    for (int i = tid; i < 8192; i += 256) ((uint32_t*)wbs)[i] = ((const uint32_t*)w2T)[i];
    barrier_lds();
    f32x4 a2[8];
    #pragma unroll
    for (int nt=0; nt<8; nt++) a2[nt] = (f32x4){0.f,0.f,0.f,0.f};
    #pragma unroll
    for (int ks=0; ks<4; ks++){
        bf16x8 af = *(const bf16x8*)&hid[(ar*128 + ks*32 + q*8) ^ ((ar&7)<<3)];
        #pragma unroll
        for (int nt=0; nt<8; nt++){
            int n = nt*16 + l16;
            bf16x8 bfr = *(const bf16x8*)&wbs[(n*128 + ks*32 + q*8) ^ ((n&7)<<3)];
            a2[nt] = mfma16(af, bfr, a2[nt]);
        }
    }
    float b2v[8], gv[8], bv[8];
    #pragma unroll
    for (int nt=0; nt<8; nt++){ int c = nt*16+l16; b2v[nt]=b2[c]; gv[nt]=gam[c]; bv[nt]=bet[c]; }
    #pragma unroll
    for (int reg=0; reg<4; reg++){
        float s=0.f, ss=0.f;
        #pragma unroll
        for (int nt=0; nt<8; nt++){ float v = a2[nt][reg] + b2v[nt]; a2[nt][reg]=v; s+=v; ss+=v*v; }
        #pragma unroll
        for (int m=1; m<16; m<<=1){ s += __shfl_xor(s,m); ss += __shfl_xor(ss,m); }
        float mean = s*(1.f/128.f);
        float rstd = __builtin_amdgcn_rsqf(ss*(1.f/128.f)-mean*mean+1e-5f);
        int row = r0 + 16*w + 4*q + reg;
        if (row < rows){
            #pragma unroll
            for (int nt=0; nt<8; nt++){
                int c = nt*16+l16;
                float o = (a2[nt][reg]-mean)*rstd*gv[nt] + bv[nt];
                if (doRelu) o = fmaxf(o, 0.f);
                h[(size_t)row*128 + c] = o;
            }
        }
    }
}

// ---------------- global mean pool ----------------
__global__ __launch_bounds__(256) void pool2_kernel(
    const float* __restrict__ h, const int* __restrict__ batch,
    float* __restrict__ gsum, float* __restrict__ cnt, int N, int npb)
{
    __shared__ float lacc[16*128];
    __shared__ float lcnt[16];
    int tid = threadIdx.x;
    int n0 = blockIdx.x * npb;
    for (int i = tid; i < 2048; i += 256) lacc[i] = 0.f;
    if (tid < 16) lcnt[tid] = 0.f;
    __syncthreads();
    int rl = tid >> 5, cg = (tid & 31) << 2;
    int cur_b = -1; float4 acc = {0.f,0.f,0.f,0.f}; float c = 0.f;
    for (int k = rl; k < npb; k += 8){
        int n = n0 + k;
        if (n >= N) break;
        int b = batch[n];
        float4 hv = *(const float4*)(h + (size_t)n*128 + cg);
        if (b != cur_b){
            if (cur_b >= 0){
                float* lp = lacc + cur_b*128 + cg;
                atomicAdd(lp+0,acc.x); atomicAdd(lp+1,acc.y); atomicAdd(lp+2,acc.z); atomicAdd(lp+3,acc.w);
                if (cg == 0) atomicAdd(&lcnt[cur_b], c);
            }
            cur_b = b; acc = hv; c = 1.f;
        } else { acc.x+=hv.x; acc.y+=hv.y; acc.z+=hv.z; acc.w+=hv.w; c += 1.f; }
    }
    if (cur_b >= 0){
        float* lp = lacc + cur_b*128 + cg;
        atomicAdd(lp+0,acc.x); atomicAdd(lp+1,acc.y); atomicAdd(lp+2,acc.z); atomicAdd(lp+3,acc.w);
        if (cg == 0) atomicAdd(&lcnt[cur_b], c);
    }
    __syncthreads();
    int lastn = n0 + npb - 1; if (lastn > N-1) lastn = N-1;
    int firstn = n0 < N-1 ? n0 : N-1;
    int bmin = batch[firstn], bmax = batch[lastn];
    int rows = bmax - bmin + 1;
    for (int i = tid; i < rows*128; i += 256){
        int b = bmin + (i >> 7), cc = i & 127;
        float v = lacc[b*128 + cc];
        if (v != 0.f) atomAddF(gsum + b*128 + cc, v);
    }
    if (tid < rows){ float v = lcnt[bmin+tid]; if (v != 0.f) atomAddF(cnt + bmin + tid, v); }
}

__global__ __launch_bounds__(256) void gproc_kernel(
    const float* __restrict__ gsum, const float* __restrict__ cnt,
    const float* __restrict__ gw, const float* __restrict__ gb,
    const float* __restrict__ gg, const float* __restrict__ gbe,
    float* __restrict__ gfin)
{
    __shared__ float gm[2048];
    int tid = threadIdx.x;
    for (int i = tid; i < 2048; i += 256){ int b = i >> 7; gm[i] = gsum[i] / fmaxf(cnt[b], 1.f); }
    __syncthreads();
    int r = tid >> 4, m = tid & 15;
    float a[8];
    #pragma unroll
    for (int j=0;j<8;j++) a[j]=0.f;
    for (int k=0;k<128;k++){
        float gv = gm[r*128+k];
        #pragma unroll
        for (int j=0;j<8;j++) a[j] = fmaf(gv, gw[k*128 + m + 16*j], a[j]);
    }
    float s=0.f, ss=0.f;
    #pragma unroll
    for (int j=0;j<8;j++){ float v = fmaxf(a[j] + gb[m+16*j], 0.f); a[j]=v; s+=v; ss+=v*v; }
    #pragma unroll
    for (int msk=1; msk<16; msk<<=1){ s += __shfl_xor(s,msk); ss += __shfl_xor(ss,msk); }
    float mean = s*(1.f/128.f);
    float rstd = __builtin_amdgcn_rsqf(ss*(1.f/128.f)-mean*mean+1e-5f);
    #pragma unroll
    for (int j=0;j<8;j++){ int c = m+16*j; gfin[r*128+c] = (a[j]-mean)*rstd*gg[c] + gbe[c]; }
}

__global__ __launch_bounds__(256) void gc_kernel(
    const float* __restrict__ gfin, const float* __restrict__ ep_w1,
    const float* __restrict__ ep_b1, float* __restrict__ Gc)
{
    __shared__ float gs[2048];
    int tid = threadIdx.x;
    for (int i = tid; i < 2048; i += 256) gs[i] = gfin[i];
    __syncthreads();
    for (int o = tid; o < 16*256; o += 256){
        int r = o >> 8, n = o & 255;
        float a = ep_b1[n];
        for (int k = 0; k < 128; k++) a = fmaf(gs[r*128+k], ep_w1[(size_t)(256+k)*256 + n], a);
        Gc[o] = a;
    }
}

// HcS = h @ W1a, HcD = h @ W1b (bf16 [N][256])
__global__ __launch_bounds__(256) void hc_prep(
    const float* __restrict__ h, const u16* __restrict__ w1aT, const u16* __restrict__ w1bT,
    u16* __restrict__ hcS, u16* __restrict__ hcD, int rows)
{
    __shared__ u16 wbs[128*128];
    int tid = threadIdx.x, r0 = blockIdx.x*64;
    int lane = tid&63, w = tid>>6, l16 = lane&15, q = lane>>4;
    int arow = r0 + 16*w + l16;
    int arc = arow < rows ? arow : rows-1;
    bf16x8 afk[4];
    #pragma unroll
    for (int ks=0; ks<4; ks++){
        const float4* hp = (const float4*)(h + (size_t)arc*128 + ks*32 + q*8);
        float4 h0 = hp[0], h1 = hp[1];
        float zv[8] = {h0.x,h0.y,h0.z,h0.w,h1.x,h1.y,h1.z,h1.w};
        afk[ks] = pack8(zv);
    }
    #pragma unroll
    for (int pass = 0; pass < 2; pass++){
        const u16* wt = pass ? w1bT : w1aT;
        f32x4 acc[16];
        #pragma unroll
        for (int i=0; i<16; i++) acc[i] = (f32x4){0.f,0.f,0.f,0.f};
        #pragma unroll
        for (int ch = 0; ch < 2; ch++){
            barrier_lds();
            for (int i = tid; i < 8192; i += 256) ((uint32_t*)wbs)[i] = ((const uint32_t*)wt)[ch*8192 + i];
            barrier_lds();
            #pragma unroll
            for (int ks=0; ks<4; ks++){
                #pragma unroll
                for (int nt=0; nt<8; nt++){
                    int n = nt*16 + l16;
                    bf16x8 bfr = *(const bf16x8*)&wbs[(n*128 + ks*32 + q*8) ^ ((n&7)<<3)];
                    acc[ch*8+nt] = mfma16(afk[ks], bfr, acc[ch*8+nt]);
                }
            }
        }
        u16* outp = pass ? hcD : hcS;
        #pragma unroll
        for (int reg=0; reg<4; reg++){
            int row = r0 + 16*w + 4*q + reg;
            if (row < rows){
                #pragma unroll
                for (int i=0; i<16; i++) outp[(size_t)row*256 + i*16 + l16] = f2bf(acc[i][reg]);
            }
        }
    }
}

// ---------------- edge predictor v5: 8KB weight chunks -> 40KB LDS -> 4 blocks/CU ----------------
#define WBS_W2() { uint4* wb4=(uint4*)wbs; wb4[tid]=pr0; wb4[tid+256]=pr1; }
#define PF_LIN(base4, ch) { const uint4* pp=(base4)+(ch)*512+tid; pr0=pp[0]; pr1=pp[256]; }
#define G2IDX2(kh,nq,u) ((((nq)*32 + ((u)>>4))*32) + (kh)*16 + ((u)&15))
#define PF_G2(kh,nq) { pr0=epw2T4[G2IDX2(kh,nq,tid)]; pr1=epw2T4[G2IDX2(kh,nq,tid+256)]; }

__global__ __launch_bounds__(256, 4) void pred_rc5(
    const float* __restrict__ ea,
    const float* __restrict__ ew1, const float* __restrict__ eb1,
    const u16* __restrict__ ew2T, const float* __restrict__ eb2,
    const float* __restrict__ eg, const float* __restrict__ ebe,
    const int* __restrict__ src, const int* __restrict__ dst, const int* __restrict__ batch,
    const u16* __restrict__ hcS, const u16* __restrict__ hcD, const float* __restrict__ Gc,
    const u16* __restrict__ w1dT, const u16* __restrict__ epw2T,
    const float* __restrict__ b2, const float* __restrict__ w3, const float* __restrict__ b3,
    float* __restrict__ out, int E)
{
    __shared__ u16 wbs[32*128];   // 8KB weight chunk (32 cols x 128 k)
    __shared__ u16 s1t[64*256];   // 32KB; lower 16KB doubles as het (e-tile transpose)
    u16* het = s1t;
    int tid = threadIdx.x, r0 = blockIdx.x*64;
    int lane = tid&63, w = tid>>6, l16 = lane&15, q = lane>>4;
    int ar = 16*w + l16;

    const uint4* ew2T4  = (const uint4*)ew2T;
    const uint4* w1dT4  = (const uint4*)w1dT;
    const uint4* epw2T4 = (const uint4*)epw2T;
    uint4 pr0, pr1;
    PF_LIN(ew2T4, 0);                              // enc chunk 0 in flight

    int rA = r0 + ar; int rAc = rA < E ? rA : E-1; // this lane's A-row edge
    int sA = src[rAc], dA = dst[rAc], gA = batch[sA];
    float ea0 = ea[(size_t)rAc*3+0], ea1 = ea[(size_t)rAc*3+1], ea2 = ea[(size_t)rAc*3+2];

    // ---- encoder hidden A-frags fully in registers (lane-local cols c = ks*32+q*8+j)
    bf16x8 ah[4];
    #pragma unroll
    for (int ks = 0; ks < 4; ks++){
        int cb = ks*32 + q*8;
        float w0[8], w1r[8], w2r[8], bb[8], hv[8];
        *(float4*)&w0[0]  = *(const float4*)(ew1 + cb);       *(float4*)&w0[4]  = *(const float4*)(ew1 + cb + 4);
        *(float4*)&w1r[0] = *(const float4*)(ew1 + 128 + cb); *(float4*)&w1r[4] = *(const float4*)(ew1 + 128 + cb + 4);
        *(float4*)&w2r[0] = *(const float4*)(ew1 + 256 + cb); *(float4*)&w2r[4] = *(const float4*)(ew1 + 256 + cb + 4);
        *(float4*)&bb[0]  = *(const float4*)(eb1 + cb);       *(float4*)&bb[4]  = *(const float4*)(eb1 + cb + 4);
        #pragma unroll
        for (int j = 0; j < 8; j++)
            hv[j] = fmaxf(bb[j] + ea0*w0[j] + ea1*w1r[j] + ea2*w2r[j], 0.f);
        ah[ks] = pack8(hv);
    }

    // ---- enc GEMM: 4 chunks of 32 cols
    f32x4 eac[8];
    #pragma unroll
    for (int i=0;i<8;i++) eac[i] = (f32x4){0.f,0.f,0.f,0.f};
    #pragma unroll
    for (int ch=0; ch<4; ch++){
        barrier_lds();                             // prev wbs reads done
        WBS_W2();
        if (ch < 3) { PF_LIN(ew2T4, ch+1); } else { PF_LIN(w1dT4, 0); }
        barrier_lds();                             // wbs visible
        #pragma unroll
        for (int ks=0; ks<4; ks++){
            #pragma unroll
            for (int nt=0; nt<2; nt++){
                int n = nt*16 + l16;
                bf16x8 bfr = *(const bf16x8*)&wbs[(n*128 + ks*32 + q*8) ^ ((n&7)<<3)];
                eac[ch*2+nt] = mfma16(ah[ks], bfr, eac[ch*2+nt]);
            }
        }
    }
    // ---- LN -> e-tile into het (swizzled); wave-local rows; paired cvt
    {
        float b2v[8], gv[8], bv[8];
        #pragma unroll
        for (int i=0;i<8;i++){ int c=i*16+l16; b2v[i]=eb2[c]; gv[i]=eg[c]; bv[i]=ebe[c]; }
        #pragma unroll
        for (int reg=0; reg<4; reg++){
            float s=0.f, ss=0.f;
            #pragma unroll
            for (int i=0;i<8;i++){ float v = eac[i][reg]+b2v[i]; eac[i][reg]=v; s+=v; ss+=v*v; }
            #pragma unroll
            for (int m=1;m<16;m<<=1){ s+=__shfl_xor(s,m); ss+=__shfl_xor(ss,m); }
            float mean = s*(1.f/128.f);
            float rstd = __builtin_amdgcn_rsqf(ss*(1.f/128.f)-mean*mean+1e-5f);
            int rl = 16*w + 4*q + reg;
            #pragma unroll
            for (int i=0;i<8;i+=2){
                float v0 = (eac[i][reg]-mean)*rstd*gv[i]+bv[i];
                float v1 = (eac[i+1][reg]-mean)*rstd*gv[i+1]+bv[i+1];
                uint32_t pk = cvt_pk_bf16(v0, v1);
                het[(rl*128 + i*16+l16) ^ ((rl&7)<<3)]     = (u16)pk;
                het[(rl*128 + (i+1)*16+l16) ^ ((rl&7)<<3)] = (u16)(pk>>16);
            }
        }
    }
    // ---- hoist e A-frags (intra-wave LDS round-trip, the only transpose needed)
    bf16x8 afE[4];
    #pragma unroll
    for (int ks=0; ks<4; ks++)
        afE[ks] = *(const bf16x8*)&het[(ar*128 + ks*32 + q*8) ^ ((ar&7)<<3)];
    asm volatile("s_waitcnt lgkmcnt(0)" ::: "memory");
    __builtin_amdgcn_sched_barrier(0);
    barrier_lds();                                 // all hoists done before s1t overwrites het bytes
    // ---- gather pre-sum: s1t[ar][c] = bf16(hcS[sA][c]+hcD[dA][c]+Gc[gA][c])
    #pragma unroll
    for (int j = 0; j < 8; j++){
        int c0 = q*64 + j*8;
        uint4 hs = *(const uint4*)(hcS + (size_t)sA*256 + c0);
        uint4 hd = *(const uint4*)(hcD + (size_t)dA*256 + c0);
        float4 g0 = *(const float4*)(Gc + gA*256 + c0);
        float4 g1 = *(const float4*)(Gc + gA*256 + c0 + 4);
        float sv[8];
        sv[0]=bf2f((u16)(hs.x&0xFFFF))+bf2f((u16)(hd.x&0xFFFF))+g0.x;
        sv[1]=bf2f((u16)(hs.x>>16))  +bf2f((u16)(hd.x>>16))  +g0.y;
        sv[2]=bf2f((u16)(hs.y&0xFFFF))+bf2f((u16)(hd.y&0xFFFF))+g0.z;
        sv[3]=bf2f((u16)(hs.y>>16))  +bf2f((u16)(hd.y>>16))  +g0.w;
        sv[4]=bf2f((u16)(hs.z&0xFFFF))+bf2f((u16)(hd.z&0xFFFF))+g1.x;
        sv[5]=bf2f((u16)(hs.z>>16))  +bf2f((u16)(hd.z>>16))  +g1.y;
        sv[6]=bf2f((u16)(hs.w&0xFFFF))+bf2f((u16)(hd.w&0xFFFF))+g1.z;
        sv[7]=bf2f((u16)(hs.w>>16))  +bf2f((u16)(hd.w>>16))  +g1.w;
        *(bf16x8*)&s1t[(ar*256 + c0) ^ ((ar&7)<<3)] = pack8(sv);
    }
    // ---- GEMM1: e @ W1d (256 cols) in TWO 128-col halves of 4 chunks each (AGPR 32)
    #pragma unroll
    for (int half = 0; half < 2; half++){
        f32x4 acc[8];
        #pragma unroll
        for (int i=0;i<8;i++) acc[i] = (f32x4){0.f,0.f,0.f,0.f};
        #pragma unroll
        for (int c4 = 0; c4 < 4; c4++){
            int ch = half*4 + c4;
            barrier_lds();
            WBS_W2();
            if (ch < 7) { PF_LIN(w1dT4, ch+1); } else { PF_G2(0,0); }
            barrier_lds();
            #pragma unroll
            for (int ks=0; ks<4; ks++){
                #pragma unroll
                for (int nt=0; nt<2; nt++){
                    int n = nt*16 + l16;
                    bf16x8 bfr = *(const bf16x8*)&wbs[(n*128 + ks*32 + q*8) ^ ((n&7)<<3)];
                    acc[c4*2+nt] = mfma16(afE[ks], bfr, acc[c4*2+nt]);
                }
            }
        }
        // epilogue for this half: += pre-summed gathers, tanh, write back (wave-local rows)
        #pragma unroll
        for (int i=0; i<8; i+=2){
            int gi0 = half*8 + i, gi1 = gi0 + 1;
            #pragma unroll
            for (int reg=0; reg<4; reg++){
                int rl = 16*w + 4*q + reg;
                int idx0 = (rl*256 + gi0*16 + l16) ^ ((rl&7)<<3);
                int idx1 = (rl*256 + gi1*16 + l16) ^ ((rl&7)<<3);
                float t0 = acc[i][reg]   + bf2f(s1t[idx0]);
                float t1 = acc[i+1][reg] + bf2f(s1t[idx1]);
                uint32_t pk = cvt_pk_bf16(fast_tanh(t0), fast_tanh(t1));
                s1t[idx0] = (u16)pk;
                s1t[idx1] = (u16)(pk>>16);
            }
        }
    }
    // ---- GEMM2: s1 @ ep_w2 (K=256 -> 128 cols), 8 chunks (kh 0..1, nq 0..3)
    f32x4 a2[8];
    #pragma unroll
    for (int i=0;i<8;i++) a2[i] = (f32x4){0.f,0.f,0.f,0.f};
    #pragma unroll
    for (int cc=0; cc<8; cc++){
        int kh = cc>>2, nq = cc&3;
        barrier_lds();
        WBS_W2();
        if (cc < 7) { int nx = cc+1; PF_G2(nx>>2, nx&3); }
        barrier_lds();
        #pragma unroll
        for (int ks=0; ks<4; ks++){
            bf16x8 af = *(const bf16x8*)&s1t[(ar*256 + kh*128 + ks*32 + q*8) ^ ((ar&7)<<3)];
            #pragma unroll
            for (int nt=0; nt<2; nt++){
                int nl = nt*16 + l16;
                bf16x8 bfr = *(const bf16x8*)&wbs[(nl*128 + ks*32 + q*8) ^ ((nl&7)<<3)];
                a2[nq*2+nt] = mfma16(af, bfr, a2[nq*2+nt]);
            }
        }
    }
    // ---- final: tanh, dot w3, 16-lane reduce, sigmoid
    float p[4] = {0.f,0.f,0.f,0.f};
    #pragma unroll
    for (int i=0;i<8;i++){
        int c = i*16 + l16;
        float b2v = b2[c], w3v = w3[c];
        #pragma unroll
        for (int reg=0;reg<4;reg++){
            float v = fast_tanh(a2[i][reg] + b2v);
            p[reg] = fmaf(v, w3v, p[reg]);
        }
    }
    float b3v = b3[0];
    #pragma unroll
    for (int reg=0;reg<4;reg++){
        float pv = p[reg];
        #pragma unroll
        for (int m=1;m<16;m<<=1) pv += __shfl_xor(pv,m);
        if (l16==0){
            int er = r0 + 16*w + 4*q + reg;
            if (er < E) out[er] = fast_sigmoid(pv + b3v);
        }
    }
}
#undef WBS_W2
#undef PF_LIN
#undef PF_G2
#undef G2IDX2

extern "C" void kernel_launch(void* const* d_in, const int* in_sizes, int n_in,
                              void* d_out, int out_size, void* d_ws, size_t ws_size,
                              hipStream_t stream)
{
    if (n_in < 33){ diag_kernel<<<1,64,0,stream>>>((float*)d_out, 2.0e6f); return; }
    const float* x      = (const float*)d_in[0];
    const float* ea     = (const float*)d_in[1];
    const int*   eidx   = (const int*)  d_in[2];
    const int*   batch  = (const int*)  d_in[3];
    const float* ne_w1  = (const float*)d_in[4];
    const float* ne_b1  = (const float*)d_in[5];
    const float* ne_w2  = (const float*)d_in[6];
    const float* ne_b2  = (const float*)d_in[7];
    const float* ne_g   = (const float*)d_in[8];
    const float* ne_be  = (const float*)d_in[9];
    const float* ee_w1  = (const float*)d_in[10];
    const float* ee_b1  = (const float*)d_in[11];
    const float* ee_w2  = (const float*)d_in[12];
    const float* ee_b2  = (const float*)d_in[13];
    const float* ee_g   = (const float*)d_in[14];
    const float* ee_be  = (const float*)d_in[15];
    const float* gin_eps= (const float*)d_in[16];
    const float* gin_w1 = (const float*)d_in[17];
    const float* gin_b1 = (const float*)d_in[18];
    const float* gin_w2 = (const float*)d_in[19];
    const float* gin_b2 = (const float*)d_in[20];
    const float* gin_g  = (const float*)d_in[21];
    const float* gin_be = (const float*)d_in[22];
    const float* gp_w   = (const float*)d_in[23];
    const float* gp_b   = (const float*)d_in[24];
    const float* gp_g   = (const float*)d_in[25];
    const float* gp_be  = (const float*)d_in[26];
    const float* ep_w1  = (const float*)d_in[27];
    const float* ep_b1  = (const float*)d_in[28];
    const float* ep_w2  = (const float*)d_in[29];
    const float* ep_b2  = (const float*)d_in[30];
    const float* ep_w3  = (const float*)d_in[31];
    const float* ep_b3  = (const float*)d_in[32];

    int N = in_sizes[0] / 3;
    int E = in_sizes[1] / 3;
    const int* srcI = eidx;
    const int* dstI = eidx + E;

    char* ws = (char*)d_ws;
    size_t off = 0;
    auto alloc = [&](size_t bytes) -> void* {
        void* p = ws + off; off += (bytes + 255) & ~(size_t)255; return p;
    };
    float* h     = (float*)alloc((size_t)N*512);
    char*  R1    = (char*) alloc((size_t)N*512);   // agg (f32 N*128) then hcS (bf16 N*256)
    u16*   hcD   = (u16*)  alloc((size_t)N*512);
    int*   deg   = (int*)  alloc((size_t)N*4);
    int*   curp  = (int*)  alloc((size_t)N*4);
    int*   src_s = (int*)  alloc((size_t)E*4);
    int*   dst_s = (int*)  alloc((size_t)E*4);
    float* ea_s  = (float*)alloc((size_t)E*12);
    float* gsum  = (float*)alloc((2048+64)*4);
    float* cnt   = gsum + 2048;
    float* gfin  = (float*)alloc(2048*4);
    float* Gc    = (float*)alloc(16*256*4);
    u16* ne_w2T = (u16*)alloc(16384*2);
    u16* ee_w2T = (u16*)alloc(16384*2);
    u16* gw1T0  = (u16*)alloc(16384*2);
    u16* gw1T1  = (u16*)alloc(16384*2);
    u16* gw2T0  = (u16*)alloc(16384*2);
    u16* gw2T1  = (u16*)alloc(16384*2);
    u16* w1aT   = (u16*)alloc(32768*2);
    u16* w1bT   = (u16*)alloc(32768*2);
    u16* w1dT   = (u16*)alloc(32768*2);
    u16* epw2T  = (u16*)alloc(32768*2);
    if (off > ws_size){
        diag_kernel<<<1,64,0,stream>>>((float*)d_out, 1.0e6f + (float)(ws_size >> 20));
        return;
    }
    float* agg = (float*)R1;
    u16*   hcS = (u16*)R1;

    // weight prep
    prep_wT<<<64, 256, 0, stream>>>(ne_w2, 128, ne_w2T, 128, 128);
    prep_wT<<<64, 256, 0, stream>>>(ee_w2, 128, ee_w2T, 128, 128);
    prep_wT<<<64, 256, 0, stream>>>(gin_w1,           128, gw1T0, 128, 128);
    prep_wT<<<64, 256, 0, stream>>>(gin_w1 + 128*128, 128, gw1T1, 128, 128);
    prep_wT<<<64, 256, 0, stream>>>(gin_w2,           128, gw2T0, 128, 128);
    prep_wT<<<64, 256, 0, stream>>>(gin_w2 + 128*128, 128, gw2T1, 128, 128);
    prep_wT<<<128,256, 0, stream>>>(ep_w1,            256, w1aT, 128, 256);
    prep_wT<<<128,256, 0, stream>>>(ep_w1 + 128*256,  256, w1bT, 128, 256);
    prep_wT<<<128,256, 0, stream>>>(ep_w1 + 384*256,  256, w1dT, 128, 256);
    prep_wT<<<128,256, 0, stream>>>(ep_w2,            128, epw2T, 256, 128);

    // CSR-by-dst build
    hipMemsetAsync(deg, 0, (size_t)N*4, stream);
    hist_kernel<<<(E+255)/256, 256, 0, stream>>>(dstI, deg, E);
    scan_kernel<<<1, 1024, 0, stream>>>(deg, curp, N);
    scatter_kernel<<<(E+255)/256, 256, 0, stream>>>(srcI, dstI, ea, curp, src_s, dst_s, ea_s, E);

    int nbN = (N + 63) / 64;
    int nbE = (E + 63) / 64;
    enc_kernel<<<nbN, 256, 0, stream>>>(x, N, ne_w1, ne_b1, ne_w2T, ne_b2, ne_g, ne_be, h);

    for (int l = 0; l < 2; l++){
        hipMemsetAsync(agg, 0, (size_t)N*512, stream);
        msg_v2<<<nbE, 256, 0, stream>>>(ea_s, src_s, dst_s,
                                        ee_w1, ee_b1, ee_w2T, ee_b2, ee_g, ee_be,
                                        h, agg, E);
        gine_update<<<nbN, 256, 0, stream>>>(h, agg, gin_eps, l,
            l ? gw1T1 : gw1T0, l ? gw2T1 : gw2T0,
            gin_b1 + l*128, gin_b2 + l*128, gin_g + l*128, gin_be + l*128,
            N, l == 0 ? 1 : 0);
    }

    hipMemsetAsync(gsum, 0, (2048 + 16) * 4, stream);
    int npb = 512;
    pool2_kernel<<<(N + npb - 1)/npb, 256, 0, stream>>>(h, batch, gsum, cnt, N, npb);
    gproc_kernel<<<1, 256, 0, stream>>>(gsum, cnt, gp_w, gp_b, gp_g, gp_be, gfin);
    gc_kernel<<<1, 256, 0, stream>>>(gfin, ep_w1, ep_b1, Gc);
    hc_prep<<<nbN, 256, 0, stream>>>(h, w1aT, w1bT, hcS, hcD, N);

    pred_rc5<<<nbE, 256, 0, stream>>>(ea, ee_w1, ee_b1, ee_w2T, ee_b2, ee_g, ee_be,
                                      srcI, dstI, batch, hcS, hcD, Gc,
                                      w1dT, epw2T, ep_b2, ep_w3, ep_b3,
                                      (float*)d_out, E);
}

// Round 11
// 2327.554 us; speedup vs baseline: 1.0676x; 1.0676x over previous
//
#include <hip/hip_runtime.h>
#include <stdint.h>

typedef unsigned short u16;
typedef short bf16x8 __attribute__((ext_vector_type(8)));
typedef float f32x4 __attribute__((ext_vector_type(4)));

#define DEV __device__ __forceinline__

DEV float bf2f(u16 u){ union{uint32_t i; float f;} v; v.i = ((uint32_t)u)<<16; return v.f; }
DEV u16 f2bf(float f){ union{float f; uint32_t i;} v; v.f=f; uint32_t u=v.i; u += 0x7FFFu + ((u>>16)&1u); return (u16)(u>>16); }
// HW packed f32->bf16 (RNE), 1 VALU op per 2 conversions
DEV uint32_t cvt_pk_bf16(float lo, float hi){
    uint32_t r;
    asm("v_cvt_pk_bf16_f32 %0, %1, %2" : "=v"(r) : "v"(lo), "v"(hi));
    return r;
}
DEV bf16x8 pack8(const float* v){
    union { bf16x8 b; uint32_t u[4]; } o;
    #pragma unroll
    for (int k=0;k<4;k++) o.u[k] = cvt_pk_bf16(v[2*k], v[2*k+1]);
    return o.b;
}
DEV float fast_tanh(float x){ float t=__builtin_amdgcn_exp2f(x*2.885390081777927f); return 1.f-2.f*__builtin_amdgcn_rcpf(t+1.f); }
DEV float fast_sigmoid(float x){ return __builtin_amdgcn_rcpf(1.f+__builtin_amdgcn_exp2f(-1.4426950408889634f*x)); }
DEV f32x4 mfma16(bf16x8 a, bf16x8 b, f32x4 c){ return __builtin_amdgcn_mfma_f32_16x16x32_bf16(a,b,c,0,0,0); }
DEV void atomAddF(float* p, float v){ __hip_atomic_fetch_add(p, v, __ATOMIC_RELAXED, __HIP_MEMORY_SCOPE_AGENT); }
// LDS-only barrier: does NOT drain vmcnt -> prefetched global loads stay in flight
DEV void barrier_lds(){
    asm volatile("s_waitcnt lgkmcnt(0)" ::: "memory");
    __builtin_amdgcn_s_barrier();
    __builtin_amdgcn_sched_barrier(0);
}

__global__ void diag_kernel(float* out, float v){ if (threadIdx.x < 8) out[threadIdx.x] = v; }

// Fused weight prep: all 10 transposes (bf16 + XOR-swizzle) in ONE launch
__global__ __launch_bounds__(256) void prep_all(
    const float* __restrict__ ne_w2, const float* __restrict__ ee_w2,
    const float* __restrict__ gin_w1, const float* __restrict__ gin_w2,
    const float* __restrict__ ep_w1, const float* __restrict__ ep_w2,
    u16* __restrict__ ne_w2T, u16* __restrict__ ee_w2T,
    u16* __restrict__ gw1T0, u16* __restrict__ gw1T1,
    u16* __restrict__ gw2T0, u16* __restrict__ gw2T1,
    u16* __restrict__ w1aT, u16* __restrict__ w1bT,
    u16* __restrict__ w1dT, u16* __restrict__ epw2T)
{
    int b = blockIdx.x, tid = threadIdx.x;
    const float* src; u16* dst; int ld, K, Nn, base;
    if      (b < 64)  { src=ne_w2;          dst=ne_w2T; ld=128; K=128; Nn=128; base=0;   }
    else if (b < 128) { src=ee_w2;          dst=ee_w2T; ld=128; K=128; Nn=128; base=64;  }
    else if (b < 192) { src=gin_w1;         dst=gw1T0;  ld=128; K=128; Nn=128; base=128; }
    else if (b < 256) { src=gin_w1+128*128; dst=gw1T1;  ld=128; K=128; Nn=128; base=192; }
    else if (b < 320) { src=gin_w2;         dst=gw2T0;  ld=128; K=128; Nn=128; base=256; }
    else if (b < 384) { src=gin_w2+128*128; dst=gw2T1;  ld=128; K=128; Nn=128; base=320; }
    else if (b < 512) { src=ep_w1;          dst=w1aT;   ld=256; K=128; Nn=256; base=384; }
    else if (b < 640) { src=ep_w1+128*256;  dst=w1bT;   ld=256; K=128; Nn=256; base=512; }
    else if (b < 768) { src=ep_w1+384*256;  dst=w1dT;   ld=256; K=128; Nn=256; base=640; }
    else              { src=ep_w2;          dst=epw2T;  ld=128; K=256; Nn=128; base=768; }
    int idx = (b-base)*256 + tid;
    if (idx >= K*Nn) return;
    int n = idx / K, k = idx - n*K;
    dst[(n*K + k) ^ ((n&7)<<3)] = f2bf(src[(size_t)k*ld + n]);
}

// ---------------- CSR-by-dst build ----------------
__global__ __launch_bounds__(256) void hist_kernel(const int* __restrict__ dst,
                                                   int* __restrict__ deg, int E)
{
    int e = blockIdx.x*256 + threadIdx.x;
    if (e < E) atomicAdd(&deg[dst[e]], 1);
}

__global__ __launch_bounds__(1024) void scan_kernel(const int* __restrict__ deg,
                                                    int* __restrict__ cur, int N)
{
    __shared__ int sc[1024];
    int t = threadIdx.x;
    int chunk = (N + 1023) / 1024;
    int i0 = t * chunk, i1 = i0 + chunk; if (i1 > N) i1 = N;
    int s = 0;
    for (int i = i0; i < i1; i++) s += deg[i];
    sc[t] = s; __syncthreads();
    int own = s;
    for (int off = 1; off < 1024; off <<= 1){
        int v = (t >= off) ? sc[t - off] : 0;
        __syncthreads();
        sc[t] += v;
        __syncthreads();
    }
    int run = sc[t] - own;
    for (int i = i0; i < i1; i++){ cur[i] = run; run += deg[i]; }
}

__global__ __launch_bounds__(256) void scatter_kernel(
    const int* __restrict__ src, const int* __restrict__ dst, const float* __restrict__ ea,
    int* __restrict__ cur, int* __restrict__ src_s, int* __restrict__ dst_s,
    float* __restrict__ ea_s, int E)
{
    int e = blockIdx.x*256 + threadIdx.x;
    if (e >= E) return;
    int d = dst[e];
    int pos = atomicAdd(&cur[d], 1);
    src_s[pos] = src[e];
    dst_s[pos] = d;
    ea_s[(size_t)pos*3+0] = ea[(size_t)e*3+0];
    ea_s[(size_t)pos*3+1] = ea[(size_t)e*3+1];
    ea_s[(size_t)pos*3+2] = ea[(size_t)e*3+2];
}

// ---------------- node encoder ----------------
__global__ __launch_bounds__(256) void enc_kernel(
    const float* __restrict__ in3, int rows,
    const float* __restrict__ w1, const float* __restrict__ b1,
    const u16* __restrict__ w2T, const float* __restrict__ b2,
    const float* __restrict__ gam, const float* __restrict__ bet,
    float* __restrict__ outF)
{
    __shared__ u16 wbs[128*128];
    __shared__ u16 hid[64*128];
    int tid = threadIdx.x, r0 = blockIdx.x*64;
    for (int i = tid; i < 8192; i += 256) ((uint32_t*)wbs)[i] = ((const uint32_t*)w2T)[i];
    for (int idx = tid; idx < 8192; idx += 256) {
        int r = idx >> 7, c = idx & 127;
        int row = r0 + r; if (row > rows-1) row = rows-1;
        float v = b1[c] + in3[(size_t)row*3+0]*w1[c] + in3[(size_t)row*3+1]*w1[128+c] + in3[(size_t)row*3+2]*w1[256+c];
        hid[idx ^ ((r&7)<<3)] = f2bf(fmaxf(v, 0.f));
    }
    barrier_lds();
    int lane = tid & 63, w = tid >> 6, l16 = lane & 15, q = lane >> 4;
    int ar = 16*w + l16;
    f32x4 acc[8];
    #pragma unroll
    for (int nt=0; nt<8; nt++) acc[nt] = (f32x4){0.f,0.f,0.f,0.f};
    #pragma unroll
    for (int ks=0; ks<4; ks++) {
        bf16x8 af = *(const bf16x8*)&hid[(ar*128 + ks*32 + q*8) ^ ((ar&7)<<3)];
        #pragma unroll
        for (int nt=0; nt<8; nt++) {
            int n = nt*16 + l16;
            bf16x8 bfr = *(const bf16x8*)&wbs[(n*128 + ks*32 + q*8) ^ ((n&7)<<3)];
            acc[nt] = mfma16(af, bfr, acc[nt]);
        }
    }
    float b2v[8], gv[8], bv[8];
    #pragma unroll
    for (int nt=0; nt<8; nt++){ int c = nt*16+l16; b2v[nt]=b2[c]; gv[nt]=gam[c]; bv[nt]=bet[c]; }
    #pragma unroll
    for (int reg=0; reg<4; reg++) {
        float s=0.f, ss=0.f;
        #pragma unroll
        for (int nt=0; nt<8; nt++){ float v = acc[nt][reg] + b2v[nt]; acc[nt][reg]=v; s+=v; ss+=v*v; }
        #pragma unroll
        for (int m=1; m<16; m<<=1){ s += __shfl_xor(s,m); ss += __shfl_xor(ss,m); }
        float mean = s * (1.f/128.f);
        float rstd = __builtin_amdgcn_rsqf(ss*(1.f/128.f) - mean*mean + 1e-5f);
        int row = r0 + 16*w + 4*q + reg;
        if (row < rows) {
            #pragma unroll
            for (int nt=0; nt<8; nt++){
                int c = nt*16+l16;
                outF[(size_t)row*128 + c] = (acc[nt][reg]-mean)*rstd*gv[nt] + bv[nt];
            }
        }
    }
}

// ---------------- dst-sorted message pass v3: T14 early h-gather ----------------
__global__ __launch_bounds__(256) void msg_v3(
    const float* __restrict__ ea_s, const int* __restrict__ src_s, const int* __restrict__ dst_s,
    const float* __restrict__ ew1, const float* __restrict__ eb1,
    const u16* __restrict__ ew2T, const float* __restrict__ eb2,
    const float* __restrict__ eg, const float* __restrict__ ebe,
    const float* __restrict__ h, float* __restrict__ agg, int E)
{
    __shared__ float lag[8192];      // 32KB: ew2T (u16) during GEMM, then f32 agg slots
    __shared__ u16 hid[64*128];      // 16KB e-tile
    __shared__ float eas[192];
    __shared__ float w1s[384];
    __shared__ float b1s[128];
    __shared__ int ssrc[64], sdv[64], sslot[64], sfl[64];
    u16* wbs = (u16*)lag;
    int tid = threadIdx.x, r0 = blockIdx.x*64;

    const uint4* w4 = (const uint4*)ew2T;
    uint4 pr[8];
    #pragma unroll
    for (int k=0;k<8;k++) pr[k] = w4[tid + k*256];

    if (tid < 192){ int gi = r0*3 + tid; eas[tid] = (gi < E*3) ? ea_s[gi] : 0.f; }
    if (tid < 128) b1s[tid] = eb1[tid];
    for (int i = tid; i < 384; i += 256) w1s[i] = ew1[i];
    if (tid < 64){
        int r = tid, ge = r0 + r;
        int valid = ge < E;
        int gc = valid ? ge : E-1;
        int dv = dst_s[gc];
        int sv = src_s[gc];
        int pin = __shfl_up(dv, 1);
        int head = (r == 0) || (dv != pin);
        int prevLast  = (r0 > 0)      ? dst_s[r0-1]  : -2;
        int nextFirst = (r0 + 64 < E) ? dst_s[r0+64] : -2;
        int interior = (dv != prevLast) && (dv != nextFirst);
        int s = head ? r : 0;
        #pragma unroll
        for (int off=1; off<64; off<<=1){ int v = __shfl_up(s, off); if (r >= off) s = (s > v ? s : v); }
        ssrc[r]=sv; sdv[r]=dv; sslot[r]=s;
        sfl[r] = ((head && valid)?1:0) | (interior?2:0) | (valid?4:0);
    }
    barrier_lds();                       // metadata/eas/w1s/b1s visible
    // T14: issue random h-gathers EARLY; latency hides under GEMM+LN (lgkm-only barriers)
    int g = tid >> 5, cgm = (tid & 31) << 2;
    float4 hv[8];
    #pragma unroll
    for (int k=0;k<8;k++)
        hv[k] = *(const float4*)(h + (size_t)ssrc[g*8+k]*128 + cgm);
    {   // write prefetched weights to LDS
        uint4* wb4 = (uint4*)wbs;
        #pragma unroll
        for (int k=0;k<8;k++) wb4[tid + k*256] = pr[k];
    }
    barrier_lds();                       // wbs visible

    int lane = tid&63, w = tid>>6, l16 = lane&15, q = lane>>4;
    int ar = 16*w + l16;
    float ea0 = eas[ar*3], ea1 = eas[ar*3+1], ea2 = eas[ar*3+2];
    f32x4 acc[8];
    #pragma unroll
    for (int nt=0; nt<8; nt++) acc[nt] = (f32x4){0.f,0.f,0.f,0.f};
    #pragma unroll
    for (int ks=0; ks<4; ks++){
        float hv8[8];
        #pragma unroll
        for (int j=0;j<8;j++){
            int c = ks*32 + q*8 + j;
            hv8[j] = fmaxf(b1s[c] + ea0*w1s[c] + ea1*w1s[128+c] + ea2*w1s[256+c], 0.f);
        }
        bf16x8 ah = pack8(hv8);
        #pragma unroll
        for (int nt=0; nt<8; nt++){
            int n = nt*16 + l16;
            bf16x8 bfr = *(const bf16x8*)&wbs[(n*128 + ks*32 + q*8) ^ ((n&7)<<3)];
            acc[nt] = mfma16(ah, bfr, acc[nt]);
        }
    }
    {   // LN -> e-tile into hid (plain layout; C/D rows wave-local)
        float b2v[8], gv[8], bv[8];
        #pragma unroll
        for (int nt=0; nt<8; nt++){ int c = nt*16+l16; b2v[nt]=eb2[c]; gv[nt]=eg[c]; bv[nt]=ebe[c]; }
        #pragma unroll
        for (int reg=0; reg<4; reg++){
            float s=0.f, ss=0.f;
            #pragma unroll
            for (int nt=0; nt<8; nt++){ float v = acc[nt][reg] + b2v[nt]; acc[nt][reg]=v; s+=v; ss+=v*v; }
            #pragma unroll
            for (int m=1; m<16; m<<=1){ s += __shfl_xor(s,m); ss += __shfl_xor(ss,m); }
            float mean = s*(1.f/128.f);
            float rstd = __builtin_amdgcn_rsqf(ss*(1.f/128.f)-mean*mean+1e-5f);
            int rl = 16*w + 4*q + reg;
            #pragma unroll
            for (int nt=0; nt<8; nt+=2){
                float v0 = (acc[nt][reg]-mean)*rstd*gv[nt] + bv[nt];
                float v1 = (acc[nt+1][reg]-mean)*rstd*gv[nt+1] + bv[nt+1];
                uint32_t pk = cvt_pk_bf16(v0, v1);
                hid[rl*128 + nt*16 + l16]     = (u16)pk;
                hid[rl*128 + (nt+1)*16 + l16] = (u16)(pk >> 16);
            }
        }
    }
    barrier_lds();
    for (int i = tid; i < 8192; i += 256) lag[i] = 0.f;
    barrier_lds();

    {   // message phase: 8 contiguous edges per thread, register run-accumulation
        float4 a = {0.f,0.f,0.f,0.f};
        int cur = -1;
        #pragma unroll
        for (int k=0;k<8;k++){
            int r = g*8 + k;
            if (sfl[r] & 4){
                uint2 ev = *(const uint2*)&hid[r*128 + cgm];
                float4 m;
                m.x = fmaxf(hv[k].x + bf2f((u16)(ev.x & 0xFFFF)), 0.f);
                m.y = fmaxf(hv[k].y + bf2f((u16)(ev.x >> 16)),   0.f);
                m.z = fmaxf(hv[k].z + bf2f((u16)(ev.y & 0xFFFF)), 0.f);
                m.w = fmaxf(hv[k].w + bf2f((u16)(ev.y >> 16)),   0.f);
                int slot = sslot[r];
                if (slot != cur){
                    if (cur >= 0){
                        float* lp = lag + cur*128 + cgm;
                        atomicAdd(lp+0,a.x); atomicAdd(lp+1,a.y); atomicAdd(lp+2,a.z); atomicAdd(lp+3,a.w);
                    }
                    cur = slot; a = m;
                } else {
                    a.x += m.x; a.y += m.y; a.z += m.z; a.w += m.w;
                }
            }
        }
        if (cur >= 0){
            float* lp = lag + cur*128 + cgm;
            atomicAdd(lp+0,a.x); atomicAdd(lp+1,a.y); atomicAdd(lp+2,a.z); atomicAdd(lp+3,a.w);
        }
    }
    barrier_lds();
    for (int t = tid; t < 2048; t += 256){
        int r = t >> 5, cg = (t & 31) << 2;
        int fl = sfl[r];
        if (!(fl & 1)) continue;
        float4 v = *(const float4*)&lag[r*128 + cg];
        float* gp = agg + (size_t)sdv[r]*128 + cg;
        if (fl & 2){ *(float4*)gp = v; }
        else { atomAddF(gp+0,v.x); atomAddF(gp+1,v.y); atomAddF(gp+2,v.z); atomAddF(gp+3,v.w); }
    }
}

// ---------------- GINE update ----------------
__global__ __launch_bounds__(256) void gine_update(
    float* h, const float* __restrict__ agg,
    const float* __restrict__ epsArr, int layer,
    const u16* __restrict__ w1T, const u16* __restrict__ w2T,
    const float* __restrict__ b1, const float* __restrict__ b2,
    const float* __restrict__ gam, const float* __restrict__ bet,
    int rows, int doRelu)
{
    __shared__ u16 wbs[128*128];
    __shared__ u16 hid[64*128];
    int tid = threadIdx.x, r0 = blockIdx.x*64;
    float epsv = 1.f + epsArr[layer];
    for (int i = tid; i < 8192; i += 256) ((uint32_t*)wbs)[i] = ((const uint32_t*)w1T)[i];
    barrier_lds();
    int lane = tid&63, w = tid>>6, l16 = lane&15, q = lane>>4;
    int ar = 16*w + l16;
    int arow = r0 + ar;
    int arc = arow < rows ? arow : rows-1;
    f32x4 acc[8];
    #pragma unroll
    for (int nt=0; nt<8; nt++) acc[nt] = (f32x4){0.f,0.f,0.f,0.f};
    #pragma unroll
    for (int ks=0; ks<4; ks++){
        const float4* hp = (const float4*)(h   + (size_t)arc*128 + ks*32 + q*8);
        const float4* ap = (const float4*)(agg + (size_t)arc*128 + ks*32 + q*8);
        float4 h0 = hp[0], h1 = hp[1], a0 = ap[0], a1 = ap[1];
        float zv[8];
        zv[0]=fmaf(epsv,h0.x,a0.x); zv[1]=fmaf(epsv,h0.y,a0.y);
        zv[2]=fmaf(epsv,h0.z,a0.z); zv[3]=fmaf(epsv,h0.w,a0.w);
        zv[4]=fmaf(epsv,h1.x,a1.x); zv[5]=fmaf(epsv,h1.y,a1.y);
        zv[6]=fmaf(epsv,h1.z,a1.z); zv[7]=fmaf(epsv,h1.w,a1.w);
        bf16x8 af = pack8(zv);
        #pragma unroll
        for (int nt=0; nt<8; nt++){
            int n = nt*16 + l16;
            bf16x8 bfr = *(const bf16x8*)&wbs[(n*128 + ks*32 + q*8) ^ ((n&7)<<3)];
            acc[nt] = mfma16(af, bfr, acc[nt]);
        }
    }
    #pragma unroll
    for (int nt=0; nt<8; nt++){
        int c = nt*16 + l16; float b1v = b1[c];
        #pragma unroll
        for (int reg=0; reg<4; reg++){
            int rl = 16*w + 4*q + reg;
            hid[(rl*128 + c) ^ ((rl&7)<<3)] = f2bf(fmaxf(acc[nt][reg] + b1v, 0.f));
        }
    }
    barrier_lds();
    for (int i = tid; i < 8192; i += 256) ((uint32_t*)wbs)[i] = ((const uint32_t*)w2T)[i];
    barrier_lds();
    f32x4 a2[8];
    #pragma unroll
    for (int nt=0; nt<8; nt++) a2[nt] = (f32x4){0.f,0.f,0.f,0.f};
    #pragma unroll
    for (int ks=0; ks<4; ks++){
        bf16x8 af = *(const bf16x8*)&hid[(ar*128 + ks*32 + q*8) ^ ((ar&7)<<3)];
        #pragma unroll
        for (int nt=0; nt<8; nt++){
            int n = nt*16 + l16;
            bf16x8 bfr = *(const bf16x8*)&wbs[(n*128 + ks*32 + q*8) ^ ((n&7)<<3)];
            a2[nt] = mfma16(af, bfr, a2[nt]);
        }
    }
    float b2v[8], gv[8], bv[8];
    #pragma unroll
    for (int nt=0; nt<8; nt++){ int c = nt*16+l16; b2v[nt]=b2[c]; gv[nt]=gam[c]; bv[nt]=bet[c]; }
    #pragma unroll
    for (int reg=0; reg<4; reg++){
        float s=0.f, ss=0.f;
        #pragma unroll
        for (int nt=0; nt<8; nt++){ float v = a2[nt][reg] + b2v[nt]; a2[nt][reg]=v; s+=v; ss+=v*v; }
        #pragma unroll
        for (int m=1; m<16; m<<=1){ s += __shfl_xor(s,m); ss += __shfl_xor(ss,m); }
        float mean = s*(1.f/128.f);
        float rstd = __builtin_amdgcn_rsqf(ss*(1.f/128.f)-mean*mean+1e-5f);
        int row = r0 + 16*w + 4*q + reg;
        if (row < rows){
            #pragma unroll
            for (int nt=0; nt<8; nt++){
                int c = nt*16+l16;
                float o = (a2[nt][reg]-mean)*rstd*gv[nt] + bv[nt];
                if (doRelu) o = fmaxf(o, 0.f);
                h[(size_t)row*128 + c] = o;
            }
        }
    }
}

// ---------------- global mean pool ----------------
__global__ __launch_bounds__(256) void pool2_kernel(
    const float* __restrict__ h, const int* __restrict__ batch,
    float* __restrict__ gsum, float* __restrict__ cnt, int N, int npb)
{
    __shared__ float lacc[16*128];
    __shared__ float lcnt[16];
    int tid = threadIdx.x;
    int n0 = blockIdx.x * npb;
    for (int i = tid; i < 2048; i += 256) lacc[i] = 0.f;
    if (tid < 16) lcnt[tid] = 0.f;
    __syncthreads();
    int rl = tid >> 5, cg = (tid & 31) << 2;
    int cur_b = -1; float4 acc = {0.f,0.f,0.f,0.f}; float c = 0.f;
    for (int k = rl; k < npb; k += 8){
        int n = n0 + k;
        if (n >= N) break;
        int b = batch[n];
        float4 hv = *(const float4*)(h + (size_t)n*128 + cg);
        if (b != cur_b){
            if (cur_b >= 0){
                float* lp = lacc + cur_b*128 + cg;
                atomicAdd(lp+0,acc.x); atomicAdd(lp+1,acc.y); atomicAdd(lp+2,acc.z); atomicAdd(lp+3,acc.w);
                if (cg == 0) atomicAdd(&lcnt[cur_b], c);
            }
            cur_b = b; acc = hv; c = 1.f;
        } else { acc.x+=hv.x; acc.y+=hv.y; acc.z+=hv.z; acc.w+=hv.w; c += 1.f; }
    }
    if (cur_b >= 0){
        float* lp = lacc + cur_b*128 + cg;
        atomicAdd(lp+0,acc.x); atomicAdd(lp+1,acc.y); atomicAdd(lp+2,acc.z); atomicAdd(lp+3,acc.w);
        if (cg == 0) atomicAdd(&lcnt[cur_b], c);
    }
    __syncthreads();
    int lastn = n0 + npb - 1; if (lastn > N-1) lastn = N-1;
    int firstn = n0 < N-1 ? n0 : N-1;
    int bmin = batch[firstn], bmax = batch[lastn];
    int rows = bmax - bmin + 1;
    for (int i = tid; i < rows*128; i += 256){
        int b = bmin + (i >> 7), cc = i & 127;
        float v = lacc[b*128 + cc];
        if (v != 0.f) atomAddF(gsum + b*128 + cc, v);
    }
    if (tid < rows){ float v = lcnt[bmin+tid]; if (v != 0.f) atomAddF(cnt + bmin + tid, v); }
}

__global__ __launch_bounds__(256) void gproc_kernel(
    const float* __restrict__ gsum, const float* __restrict__ cnt,
    const float* __restrict__ gw, const float* __restrict__ gb,
    const float* __restrict__ gg, const float* __restrict__ gbe,
    float* __restrict__ gfin)
{
    __shared__ float gm[2048];
    int tid = threadIdx.x;
    for (int i = tid; i < 2048; i += 256){ int b = i >> 7; gm[i] = gsum[i] / fmaxf(cnt[b], 1.f); }
    __syncthreads();
    int r = tid >> 4, m = tid & 15;
    float a[8];
    #pragma unroll
    for (int j=0;j<8;j++) a[j]=0.f;
    for (int k=0;k<128;k++){
        float gv = gm[r*128+k];
        #pragma unroll
        for (int j=0;j<8;j++) a[j] = fmaf(gv, gw[k*128 + m + 16*j], a[j]);
    }
    float s=0.f, ss=0.f;
    #pragma unroll
    for (int j=0;j<8;j++){ float v = fmaxf(a[j] + gb[m+16*j], 0.f); a[j]=v; s+=v; ss+=v*v; }
    #pragma unroll
    for (int msk=1; msk<16; msk<<=1){ s += __shfl_xor(s,msk); ss += __shfl_xor(ss,msk); }
    float mean = s*(1.f/128.f);
    float rstd = __builtin_amdgcn_rsqf(ss*(1.f/128.f)-mean*mean+1e-5f);
    #pragma unroll
    for (int j=0;j<8;j++){ int c = m+16*j; gfin[r*128+c] = (a[j]-mean)*rstd*gg[c] + gbe[c]; }
}

__global__ __launch_bounds__(256) void gc_kernel(
    const float* __restrict__ gfin, const float* __restrict__ ep_w1,
    const float* __restrict__ ep_b1, float* __restrict__ Gc)
{
    __shared__ float gs[2048];
    int tid = threadIdx.x;
    for (int i = tid; i < 2048; i += 256) gs[i] = gfin[i];
    __syncthreads();
    for (int o = tid; o < 16*256; o += 256){
        int r = o >> 8, n = o & 255;
        float a = ep_b1[n];
        for (int k = 0; k < 128; k++) a = fmaf(gs[r*128+k], ep_w1[(size_t)(256+k)*256 + n], a);
        Gc[o] = a;
    }
}

// HcS = h @ W1a, HcD = h @ W1b (bf16 [N][256])
__global__ __launch_bounds__(256) void hc_prep(
    const float* __restrict__ h, const u16* __restrict__ w1aT, const u16* __restrict__ w1bT,
    u16* __restrict__ hcS, u16* __restrict__ hcD, int rows)
{
    __shared__ u16 wbs[128*128];
    int tid = threadIdx.x, r0 = blockIdx.x*64;
    int lane = tid&63, w = tid>>6, l16 = lane&15, q = lane>>4;
    int arow = r0 + 16*w + l16;
    int arc = arow < rows ? arow : rows-1;
    bf16x8 afk[4];
    #pragma unroll
    for (int ks=0; ks<4; ks++){
        const float4* hp = (const float4*)(h + (size_t)arc*128 + ks*32 + q*8);
        float4 h0 = hp[0], h1 = hp[1];
        float zv[8] = {h0.x,h0.y,h0.z,h0.w,h1.x,h1.y,h1.z,h1.w};
        afk[ks] = pack8(zv);
    }
    #pragma unroll
    for (int pass = 0; pass < 2; pass++){
        const u16* wt = pass ? w1bT : w1aT;
        f32x4 acc[16];
        #pragma unroll
        for (int i=0; i<16; i++) acc[i] = (f32x4){0.f,0.f,0.f,0.f};
        #pragma unroll
        for (int ch = 0; ch < 2; ch++){
            barrier_lds();
            for (int i = tid; i < 8192; i += 256) ((uint32_t*)wbs)[i] = ((const uint32_t*)wt)[ch*8192 + i];
            barrier_lds();
            #pragma unroll
            for (int ks=0; ks<4; ks++){
                #pragma unroll
                for (int nt=0; nt<8; nt++){
                    int n = nt*16 + l16;
                    bf16x8 bfr = *(const bf16x8*)&wbs[(n*128 + ks*32 + q*8) ^ ((n&7)<<3)];
                    acc[ch*8+nt] = mfma16(afk[ks], bfr, acc[ch*8+nt]);
                }
            }
        }
        u16* outp = pass ? hcD : hcS;
        #pragma unroll
        for (int reg=0; reg<4; reg++){
            int row = r0 + 16*w + 4*q + reg;
            if (row < rows){
                #pragma unroll
                for (int i=0; i<16; i++) outp[(size_t)row*256 + i*16 + l16] = f2bf(acc[i][reg]);
            }
        }
    }
}

// ---------------- edge predictor v4 (REVERTED from rc5 regression): 16KB chunks, 3 blocks/CU ----------------
#define WBS_WRITE() { uint4* wb4=(uint4*)wbs; wb4[tid]=pr0; wb4[tid+256]=pr1; wb4[tid+512]=pr2; wb4[tid+768]=pr3; }
#define PREFETCH_LIN(base4, ch) { const uint4* pp=(base4)+(ch)*1024+tid; pr0=pp[0]; pr1=pp[256]; pr2=pp[512]; pr3=pp[768]; }
#define G2IDX(kh,nh,u) ((((nh)*64 + ((u)>>4))*32) + (kh)*16 + ((u)&15))
#define PREFETCH_G2(kh,nh) { pr0=epw2T4[G2IDX(kh,nh,tid)]; pr1=epw2T4[G2IDX(kh,nh,tid+256)]; pr2=epw2T4[G2IDX(kh,nh,tid+512)]; pr3=epw2T4[G2IDX(kh,nh,tid+768)]; }

__global__ __launch_bounds__(256, 3) void pred_rc4(
    const float* __restrict__ ea,
    const float* __restrict__ ew1, const float* __restrict__ eb1,
    const u16* __restrict__ ew2T, const float* __restrict__ eb2,
    const float* __restrict__ eg, const float* __restrict__ ebe,
    const int* __restrict__ src, const int* __restrict__ dst, const int* __restrict__ batch,
    const u16* __restrict__ hcS, const u16* __restrict__ hcD, const float* __restrict__ Gc,
    const u16* __restrict__ w1dT, const u16* __restrict__ epw2T,
    const float* __restrict__ b2, const float* __restrict__ w3, const float* __restrict__ b3,
    float* __restrict__ out, int E)
{
    __shared__ u16 wbs[64*128];   // 16KB weight chunk
    __shared__ u16 s1t[64*256];   // 32KB; lower 16KB doubles as het (e-tile transpose)
    u16* het = s1t;
    int tid = threadIdx.x, r0 = blockIdx.x*64;
    int lane = tid&63, w = tid>>6, l16 = lane&15, q = lane>>4;
    int ar = 16*w + l16;

    const uint4* ew2T4  = (const uint4*)ew2T;
    const uint4* w1dT4  = (const uint4*)w1dT;
    const uint4* epw2T4 = (const uint4*)epw2T;
    uint4 pr0, pr1, pr2, pr3;
    PREFETCH_LIN(ew2T4, 0);                       // enc chunk 0 in flight

    int rA = r0 + ar; int rAc = rA < E ? rA : E-1;     // this lane's A-row edge
    int sA = src[rAc], dA = dst[rAc], gA = batch[sA];
    float ea0 = ea[(size_t)rAc*3+0], ea1 = ea[(size_t)rAc*3+1], ea2 = ea[(size_t)rAc*3+2];

    // ---- encoder hidden A-frags fully in registers (lane-local cols c = ks*32+q*8+j)
    bf16x8 ah[4];
    #pragma unroll
    for (int ks = 0; ks < 4; ks++){
        int cb = ks*32 + q*8;
        float w0[8], w1r[8], w2r[8], bb[8], hv[8];
        *(float4*)&w0[0]  = *(const float4*)(ew1 + cb);       *(float4*)&w0[4]  = *(const float4*)(ew1 + cb + 4);
        *(float4*)&w1r[0] = *(const float4*)(ew1 + 128 + cb); *(float4*)&w1r[4] = *(const float4*)(ew1 + 128 + cb + 4);
        *(float4*)&w2r[0] = *(const float4*)(ew1 + 256 + cb); *(float4*)&w2r[4] = *(const float4*)(ew1 + 256 + cb + 4);
        *(float4*)&bb[0]  = *(const float4*)(eb1 + cb);       *(float4*)&bb[4]  = *(const float4*)(eb1 + cb + 4);
        #pragma unroll
        for (int j = 0; j < 8; j++)
            hv[j] = fmaxf(bb[j] + ea0*w0[j] + ea1*w1r[j] + ea2*w2r[j], 0.f);
        ah[ks] = pack8(hv);
    }

    // ---- enc GEMM: 2 chunks of 64 cols
    f32x4 eac[8];
    #pragma unroll
    for (int i=0;i<8;i++) eac[i] = (f32x4){0.f,0.f,0.f,0.f};
    #pragma unroll
    for (int ch=0; ch<2; ch++){
        barrier_lds();                             // prev wbs reads done
        WBS_WRITE();
        if (ch == 0) { PREFETCH_LIN(ew2T4, 1); } else { PREFETCH_LIN(w1dT4, 0); }
        barrier_lds();                             // wbs visible
        #pragma unroll
        for (int ks=0; ks<4; ks++){
            #pragma unroll
            for (int nt=0; nt<4; nt++){
                int n = nt*16 + l16;
                bf16x8 bfr = *(const bf16x8*)&wbs[(n*128 + ks*32 + q*8) ^ ((n&7)<<3)];
                eac[ch*4+nt] = mfma16(ah[ks], bfr, eac[ch*4+nt]);
            }
        }
    }
    // ---- LN -> e-tile into het (swizzled); wave-local rows; paired cvt
    {
        float b2v[8], gv[8], bv[8];
        #pragma unroll
        for (int i=0;i<8;i++){ int c=i*16+l16; b2v[i]=eb2[c]; gv[i]=eg[c]; bv[i]=ebe[c]; }
        #pragma unroll
        for (int reg=0; reg<4; reg++){
            float s=0.f, ss=0.f;
            #pragma unroll
            for (int i=0;i<8;i++){ float v = eac[i][reg]+b2v[i]; eac[i][reg]=v; s+=v; ss+=v*v; }
            #pragma unroll
            for (int m=1;m<16;m<<=1){ s+=__shfl_xor(s,m); ss+=__shfl_xor(ss,m); }
            float mean = s*(1.f/128.f);
            float rstd = __builtin_amdgcn_rsqf(ss*(1.f/128.f)-mean*mean+1e-5f);
            int rl = 16*w + 4*q + reg;
            #pragma unroll
            for (int i=0;i<8;i+=2){
                float v0 = (eac[i][reg]-mean)*rstd*gv[i]+bv[i];
                float v1 = (eac[i+1][reg]-mean)*rstd*gv[i+1]+bv[i+1];
                uint32_t pk = cvt_pk_bf16(v0, v1);
                het[(rl*128 + i*16+l16) ^ ((rl&7)<<3)]     = (u16)pk;
                het[(rl*128 + (i+1)*16+l16) ^ ((rl&7)<<3)] = (u16)(pk>>16);
            }
        }
    }
    // ---- hoist e A-frags (intra-wave LDS round-trip, the only transpose needed)
    bf16x8 afE[4];
    #pragma unroll
    for (int ks=0; ks<4; ks++)
        afE[ks] = *(const bf16x8*)&het[(ar*128 + ks*32 + q*8) ^ ((ar&7)<<3)];
    asm volatile("s_waitcnt lgkmcnt(0)" ::: "memory");
    __builtin_amdgcn_sched_barrier(0);
    barrier_lds();                                 // all hoists done before s1t overwrites het bytes
    // ---- gather pre-sum: s1t[ar][c] = bf16(hcS[sA][c]+hcD[dA][c]+Gc[gA][c])
    #pragma unroll
    for (int j = 0; j < 8; j++){
        int c0 = q*64 + j*8;
        uint4 hs = *(const uint4*)(hcS + (size_t)sA*256 + c0);
        uint4 hd = *(const uint4*)(hcD + (size_t)dA*256 + c0);
        float4 g0 = *(const float4*)(Gc + gA*256 + c0);
        float4 g1 = *(const float4*)(Gc + gA*256 + c0 + 4);
        float sv[8];
        sv[0]=bf2f((u16)(hs.x&0xFFFF))+bf2f((u16)(hd.x&0xFFFF))+g0.x;
        sv[1]=bf2f((u16)(hs.x>>16))  +bf2f((u16)(hd.x>>16))  +g0.y;
        sv[2]=bf2f((u16)(hs.y&0xFFFF))+bf2f((u16)(hd.y&0xFFFF))+g0.z;
        sv[3]=bf2f((u16)(hs.y>>16))  +bf2f((u16)(hd.y>>16))  +g0.w;
        sv[4]=bf2f((u16)(hs.z&0xFFFF))+bf2f((u16)(hd.z&0xFFFF))+g1.x;
        sv[5]=bf2f((u16)(hs.z>>16))  +bf2f((u16)(hd.z>>16))  +g1.y;
        sv[6]=bf2f((u16)(hs.w&0xFFFF))+bf2f((u16)(hd.w&0xFFFF))+g1.z;
        sv[7]=bf2f((u16)(hs.w>>16))  +bf2f((u16)(hd.w>>16))  +g1.w;
        *(bf16x8*)&s1t[(ar*256 + c0) ^ ((ar&7)<<3)] = pack8(sv);
    }
    // ---- GEMM1: e @ W1d (256 cols) in TWO 128-col halves, acc[8] each (AGPR 64->32)
    #pragma unroll
    for (int half = 0; half < 2; half++){
        f32x4 acc[8];
        #pragma unroll
        for (int i=0;i<8;i++) acc[i] = (f32x4){0.f,0.f,0.f,0.f};
        #pragma unroll
        for (int c2 = 0; c2 < 2; c2++){
            int ch = half*2 + c2;
            barrier_lds();
            WBS_WRITE();
            if (ch < 3) { PREFETCH_LIN(w1dT4, ch+1); } else { PREFETCH_G2(0,0); }
            barrier_lds();
            #pragma unroll
            for (int ks=0; ks<4; ks++){
                #pragma unroll
                for (int nt=0; nt<4; nt++){
                    int n = nt*16 + l16;
                    bf16x8 bfr = *(const bf16x8*)&wbs[(n*128 + ks*32 + q*8) ^ ((n&7)<<3)];
                    acc[c2*4+nt] = mfma16(afE[ks], bfr, acc[c2*4+nt]);
                }
            }
        }
        // epilogue for this half: += pre-summed gathers, tanh, write back (wave-local rows)
        #pragma unroll
        for (int i=0; i<8; i+=2){
            int gi0 = half*8 + i, gi1 = gi0 + 1;
            #pragma unroll
            for (int reg=0; reg<4; reg++){
                int rl = 16*w + 4*q + reg;
                int idx0 = (rl*256 + gi0*16 + l16) ^ ((rl&7)<<3);
                int idx1 = (rl*256 + gi1*16 + l16) ^ ((rl&7)<<3);
                float t0 = acc[i][reg]   + bf2f(s1t[idx0]);
                float t1 = acc[i+1][reg] + bf2f(s1t[idx1]);
                uint32_t pk = cvt_pk_bf16(fast_tanh(t0), fast_tanh(t1));
                s1t[idx0] = (u16)pk;
                s1t[idx1] = (u16)(pk>>16);
            }
        }
    }
    // ---- GEMM2: s1 @ ep_w2 (K=256 -> 128 cols), 4 chunks (kh,nh)
    f32x4 a2[8];
    #pragma unroll
    for (int i=0;i<8;i++) a2[i] = (f32x4){0.f,0.f,0.f,0.f};
    #pragma unroll
    for (int cc=0; cc<4; cc++){
        int kh = cc>>1, nh = cc&1;
        barrier_lds();
        WBS_WRITE();
        if (cc == 0) { PREFETCH_G2(0,1); } else if (cc == 1) { PREFETCH_G2(1,0); } else if (cc == 2) { PREFETCH_G2(1,1); }
        barrier_lds();
        #pragma unroll
        for (int ks=0; ks<4; ks++){
            bf16x8 af = *(const bf16x8*)&s1t[(ar*256 + kh*128 + ks*32 + q*8) ^ ((ar&7)<<3)];
            #pragma unroll
            for (int nt=0; nt<4; nt++){
                int nl = nt*16 + l16;
                bf16x8 bfr = *(const bf16x8*)&wbs[(nl*128 + ks*32 + q*8) ^ ((nl&7)<<3)];
                a2[nh*4+nt] = mfma16(af, bfr, a2[nh*4+nt]);
            }
        }
    }
    // ---- final: tanh, dot w3, 16-lane reduce, sigmoid
    float p[4] = {0.f,0.f,0.f,0.f};
    #pragma unroll
    for (int i=0;i<8;i++){
        int c = i*16 + l16;
        float b2v = b2[c], w3v = w3[c];
        #pragma unroll
        for (int reg=0;reg<4;reg++){
            float v = fast_tanh(a2[i][reg] + b2v);
            p[reg] = fmaf(v, w3v, p[reg]);
        }
    }
    float b3v = b3[0];
    #pragma unroll
    for (int reg=0;reg<4;reg++){
        float pv = p[reg];
        #pragma unroll
        for (int m=1;m<16;m<<=1) pv += __shfl_xor(pv,m);
        if (l16==0){
            int er = r0 + 16*w + 4*q + reg;
            if (er < E) out[er] = fast_sigmoid(pv + b3v);
        }
    }
}
#undef WBS_WRITE
#undef PREFETCH_LIN
#undef PREFETCH_G2
#undef G2IDX

extern "C" void kernel_launch(void* const* d_in, const int* in_sizes, int n_in,
                              void* d_out, int out_size, void* d_ws, size_t ws_size,
                              hipStream_t stream)
{
    if (n_in < 33){ diag_kernel<<<1,64,0,stream>>>((float*)d_out, 2.0e6f); return; }
    const float* x      = (const float*)d_in[0];
    const float* ea     = (const float*)d_in[1];
    const int*   eidx   = (const int*)  d_in[2];
    const int*   batch  = (const int*)  d_in[3];
    const float* ne_w1  = (const float*)d_in[4];
    const float* ne_b1  = (const float*)d_in[5];
    const float* ne_w2  = (const float*)d_in[6];
    const float* ne_b2  = (const float*)d_in[7];
    const float* ne_g   = (const float*)d_in[8];
    const float* ne_be  = (const float*)d_in[9];
    const float* ee_w1  = (const float*)d_in[10];
    const float* ee_b1  = (const float*)d_in[11];
    const float* ee_w2  = (const float*)d_in[12];
    const float* ee_b2  = (const float*)d_in[13];
    const float* ee_g   = (const float*)d_in[14];
    const float* ee_be  = (const float*)d_in[15];
    const float* gin_eps= (const float*)d_in[16];
    const float* gin_w1 = (const float*)d_in[17];
    const float* gin_b1 = (const float*)d_in[18];
    const float* gin_w2 = (const float*)d_in[19];
    const float* gin_b2 = (const float*)d_in[20];
    const float* gin_g  = (const float*)d_in[21];
    const float* gin_be = (const float*)d_in[22];
    const float* gp_w   = (const float*)d_in[23];
    const float* gp_b   = (const float*)d_in[24];
    const float* gp_g   = (const float*)d_in[25];
    const float* gp_be  = (const float*)d_in[26];
    const float* ep_w1  = (const float*)d_in[27];
    const float* ep_b1  = (const float*)d_in[28];
    const float* ep_w2  = (const float*)d_in[29];
    const float* ep_b2  = (const float*)d_in[30];
    const float* ep_w3  = (const float*)d_in[31];
    const float* ep_b3  = (const float*)d_in[32];

    int N = in_sizes[0] / 3;
    int E = in_sizes[1] / 3;
    const int* srcI = eidx;
    const int* dstI = eidx + E;

    char* ws = (char*)d_ws;
    size_t off = 0;
    auto alloc = [&](size_t bytes) -> void* {
        void* p = ws + off; off += (bytes + 255) & ~(size_t)255; return p;
    };
    float* h     = (float*)alloc((size_t)N*512);
    char*  R1    = (char*) alloc((size_t)N*512);   // agg (f32 N*128) then hcS (bf16 N*256)
    u16*   hcD   = (u16*)  alloc((size_t)N*512);
    int*   deg   = (int*)  alloc((size_t)N*4);
    int*   curp  = (int*)  alloc((size_t)N*4);
    int*   src_s = (int*)  alloc((size_t)E*4);
    int*   dst_s = (int*)  alloc((size_t)E*4);
    float* ea_s  = (float*)alloc((size_t)E*12);
    float* gsum  = (float*)alloc((2048+64)*4);
    float* cnt   = gsum + 2048;
    float* gfin  = (float*)alloc(2048*4);
    float* Gc    = (float*)alloc(16*256*4);
    u16* ne_w2T = (u16*)alloc(16384*2);
    u16* ee_w2T = (u16*)alloc(16384*2);
    u16* gw1T0  = (u16*)alloc(16384*2);
    u16* gw1T1  = (u16*)alloc(16384*2);
    u16* gw2T0  = (u16*)alloc(16384*2);
    u16* gw2T1  = (u16*)alloc(16384*2);
    u16* w1aT   = (u16*)alloc(32768*2);
    u16* w1bT   = (u16*)alloc(32768*2);
    u16* w1dT   = (u16*)alloc(32768*2);
    u16* epw2T  = (u16*)alloc(32768*2);
    if (off > ws_size){
        diag_kernel<<<1,64,0,stream>>>((float*)d_out, 1.0e6f + (float)(ws_size >> 20));
        return;
    }
    float* agg = (float*)R1;
    u16*   hcS = (u16*)R1;

    // fused weight prep (1 launch instead of 10)
    prep_all<<<896, 256, 0, stream>>>(ne_w2, ee_w2, gin_w1, gin_w2, ep_w1, ep_w2,
                                      ne_w2T, ee_w2T, gw1T0, gw1T1, gw2T0, gw2T1,
                                      w1aT, w1bT, w1dT, epw2T);

    // CSR-by-dst build
    hipMemsetAsync(deg, 0, (size_t)N*4, stream);
    hist_kernel<<<(E+255)/256, 256, 0, stream>>>(dstI, deg, E);
    scan_kernel<<<1, 1024, 0, stream>>>(deg, curp, N);
    scatter_kernel<<<(E+255)/256, 256, 0, stream>>>(srcI, dstI, ea, curp, src_s, dst_s, ea_s, E);

    int nbN = (N + 63) / 64;
    int nbE = (E + 63) / 64;
    enc_kernel<<<nbN, 256, 0, stream>>>(x, N, ne_w1, ne_b1, ne_w2T, ne_b2, ne_g, ne_be, h);

    for (int l = 0; l < 2; l++){
        hipMemsetAsync(agg, 0, (size_t)N*512, stream);
        msg_v3<<<nbE, 256, 0, stream>>>(ea_s, src_s, dst_s,
                                        ee_w1, ee_b1, ee_w2T, ee_b2, ee_g, ee_be,
                                        h, agg, E);
        gine_update<<<nbN, 256, 0, stream>>>(h, agg, gin_eps, l,
            l ? gw1T1 : gw1T0, l ? gw2T1 : gw2T0,
            gin_b1 + l*128, gin_b2 + l*128, gin_g + l*128, gin_be + l*128,
            N, l == 0 ? 1 : 0);
    }

    hipMemsetAsync(gsum, 0, (2048 + 16) * 4, stream);
    int npb = 512;
    pool2_kernel<<<(N + npb - 1)/npb, 256, 0, stream>>>(h, batch, gsum, cnt, N, npb);
    gproc_kernel<<<1, 256, 0, stream>>>(gsum, cnt, gp_w, gp_b, gp_g, gp_be, gfin);
    gc_kernel<<<1, 256, 0, stream>>>(gfin, ep_w1, ep_b1, Gc);
    hc_prep<<<nbN, 256, 0, stream>>>(h, w1aT, w1bT, hcS, hcD, N);

    pred_rc4<<<nbE, 256, 0, stream>>>(ea, ee_w1, ee_b1, ee_w2T, ee_b2, ee_g, ee_be,
                                      srcI, dstI, batch, hcS, hcD, Gc,
                                      w1dT, epw2T, ep_b2, ep_w3, ep_b3,
                                      (float*)d_out, E);
}